// Round 3
// baseline (181.465 us; speedup 1.0000x reference)
//
#include <hip/hip_runtime.h>
#include <math.h>

#define BS 32
#define KP 1000
#define KG 100
#define NC 80
#define SK 96            // padded K stride (bf16 elements per alpha row)
#define NT 8             // ceil(KP/128) tiles of 128
#define NPAIR 36         // NT*(NT+1)/2
#define NBLK (BS * NPAIR)

using bf16x8 = __attribute__((ext_vector_type(8))) short;
using f32x4  = __attribute__((ext_vector_type(4))) float;

__device__ __forceinline__ float wave_reduce_sum(float v) {
#pragma unroll
    for (int m = 32; m > 0; m >>= 1) v += __shfl_xor(v, m, 64);
    return v;
}
__device__ __forceinline__ float wave_reduce_max(float v) {
#pragma unroll
    for (int m = 32; m > 0; m >>= 1) v = fmaxf(v, __shfl_xor(v, m, 64));
    return v;
}

__device__ __forceinline__ unsigned short f2bf(float f) {   // RN-even, benign values
    unsigned int u = __float_as_uint(f);
    u += 0x7fffu + ((u >> 16) & 1u);
    return (unsigned short)(u >> 16);
}
__device__ __forceinline__ float bf2f(unsigned short h) {
    return __uint_as_float(((unsigned int)h) << 16);
}

// K_ij = N(m_i; m_j, v_i+v_j), diagonal 2-D. a,b = (mx, my, vx, vy)
__device__ __forceinline__ float kval(float4 a, float4 b) {
    float Sx = a.z + b.z, Sy = a.w + b.w;
    float ix = 1.0f / Sx, iy = 1.0f / Sy;
    float dx = a.x - b.x, dy = a.y - b.y;
    return 0.15915494309189535f * sqrtf(ix * iy) *
           __expf(-0.5f * (dx * dx * ix + dy * dy * iy));
}

// alpha[row][c] = sigmoid(l[80]) * softmax(l[0..79]); write bf16 hi/lo split,
// K padded 80->96 with zeros. One wave per row. Block 0 zeroes acc[128]
// (pq[32], pp[32], qq[32], counter, pad).
__global__ __launch_bounds__(256) void alpha_kernel(const float* __restrict__ pl,
                                                    unsigned short* __restrict__ ah,
                                                    unsigned short* __restrict__ al,
                                                    float* __restrict__ acc) {
    if (blockIdx.x == 0 && threadIdx.x < 128) acc[threadIdx.x] = 0.0f;
    int wave = threadIdx.x >> 6;
    int lane = threadIdx.x & 63;
    int row = blockIdx.x * 4 + wave;                  // < BS*KP = 32000
    const float* x = pl + (size_t)row * (NC + 1);
    float l0 = x[lane];
    float l1 = (lane < 16) ? x[64 + lane] : -1e30f;
    float obj = x[NC];
    float m = wave_reduce_max(fmaxf(l0, l1));
    float e0 = __expf(l0 - m);
    float e1 = (lane < 16) ? __expf(l1 - m) : 0.0f;
    float s = wave_reduce_sum(e0 + e1);
    float sig = 1.0f / (1.0f + __expf(-obj));
    float sc = sig / s;

    float v0 = e0 * sc;
    float v1 = e1 * sc;
    unsigned short h0 = f2bf(v0);
    unsigned short g0 = f2bf(v0 - bf2f(h0));
    unsigned short h1 = f2bf(v1);
    unsigned short g1 = f2bf(v1 - bf2f(h1));

    unsigned short* oh = ah + (size_t)row * SK;
    unsigned short* ol = al + (size_t)row * SK;
    oh[lane] = h0;
    ol[lane] = g0;
    if (lane < 32) {                 // k = 64..95 (last 16 are zero pad)
        oh[64 + lane] = (lane < 16) ? h1 : 0;
        ol[64 + lane] = (lane < 16) ? g1 : 0;
    }
}

// Fused pp + pq. grid (5, BS): blockIdx.x<4 -> pq chunk of 256 pred j's; ==4 -> pp.
__global__ __launch_bounds__(256) void ppq_kernel(const float* __restrict__ pb,
                                                  const unsigned short* __restrict__ ah,
                                                  const unsigned short* __restrict__ al,
                                                  const float* __restrict__ gtb,
                                                  const int* __restrict__ gtl,
                                                  float* __restrict__ acc_pq,
                                                  float* __restrict__ acc_pp) {
    __shared__ float4 gm[KG];
    __shared__ int gl[KG];
    __shared__ float red[256];
    int b = blockIdx.y;
    int tid = threadIdx.x;
    if (tid < KG) {
        float4 x = ((const float4*)gtb)[b * KG + tid];
        gm[tid] = make_float4(x.x, x.y, 0.25f * x.z * x.z, 0.25f * x.w * x.w);
        gl[tid] = gtl[b * KG + tid];
    }
    __syncthreads();
    float part = 0.0f;
    if (blockIdx.x < 4) {
        int j = blockIdx.x * 256 + tid;
        if (j < KP) {
            float4 x = ((const float4*)pb)[b * KP + j];
            float4 pm = make_float4(x.x, x.y, 0.25f * x.z * x.z, 0.25f * x.w * x.w);
            const unsigned short* rh = ah + ((size_t)b * KP + j) * SK;
            const unsigned short* rl = al + ((size_t)b * KP + j) * SK;
#pragma unroll 4
            for (int i = 0; i < KG; ++i) {
                int c = gl[i];
                float a = bf2f(rh[c]) + bf2f(rl[c]);
                part += a * kval(gm[i], pm);
            }
        }
    } else {
        for (int p = tid; p < KG * KG; p += 256) {
            int i = p / KG;
            int j = p - i * KG;
            if (gl[i] == gl[j]) part += kval(gm[i], gm[j]);
        }
    }
    red[tid] = part;
    __syncthreads();
#pragma unroll
    for (int s = 128; s > 0; s >>= 1) {
        if (tid < s) red[tid] += red[tid + s];
        __syncthreads();
    }
    if (tid == 0) {
        if (blockIdx.x < 4) atomicAdd(&acc_pq[b], red[0]);
        else acc_pp[b] = red[0];
    }
}

__device__ __forceinline__ bf16x8 load8(const unsigned short* __restrict__ p,
                                        int row, int kk) {
    if (row < KP) return *(const bf16x8*)(p + (size_t)row * SK + kk);
    bf16x8 z = {0, 0, 0, 0, 0, 0, 0, 0};
    return z;
}

// qq: per image, sum over 1000x1000 pred pairs, w = dot80(alpha_i, alpha_j).
// MFMA bf16 hi/lo split Gram matrix: C = Ah*Ah^T + Ah*Al^T + Al*Ah^T.
// 128x128 block tile (triangular, off-diag x2), 4 waves of 64x64, fragments
// loaded straight from global (L1/L2). Epilogue applies kval per pair.
// Last block (atomic counter) computes the final loss.
__global__ __launch_bounds__(256) void qq_kernel(const float* __restrict__ pb,
                                                 const unsigned short* __restrict__ ahg,
                                                 const unsigned short* __restrict__ alg,
                                                 float* __restrict__ acc,
                                                 float* __restrict__ out) {
    __shared__ float prm[8][128];   // [0..3]=a-side mx,my,vx,vy ; [4..7]=b-side
    __shared__ float red[256];
    __shared__ int last;

    int bi = blockIdx.x;
    int b = bi / NPAIR;
    int t = bi - b * NPAIR;
    int it = 0, rem = t;
    while (rem >= NT - it) { rem -= NT - it; ++it; }
    int jt = it + rem;
    int i0 = it * 128, j0 = jt * 128;

    int tid = threadIdx.x;

    // stage per-row params (m, v) as SoA
    {
        int side = tid >> 7, r = tid & 127;
        int gi = (side ? j0 : i0) + r;
        float4 v = make_float4(0.0f, 0.0f, 1.0f, 1.0f);
        if (gi < KP) {
            float4 x = ((const float4*)pb)[b * KP + gi];
            v = make_float4(x.x, x.y, 0.25f * x.z * x.z, 0.25f * x.w * x.w);
        }
        prm[side * 4 + 0][r] = v.x;
        prm[side * 4 + 1][r] = v.y;
        prm[side * 4 + 2][r] = v.z;
        prm[side * 4 + 3][r] = v.w;
    }
    __syncthreads();

    const unsigned short* ah = ahg + (size_t)b * KP * SK;
    const unsigned short* al = alg + (size_t)b * KP * SK;

    int lane = tid & 63, w = tid >> 6;
    int wy = w >> 1, wx = w & 1;
    int m15 = lane & 15, quad = lane >> 4;
    int arow = i0 + wy * 64 + m15;   // + rg*16
    int brow = j0 + wx * 64 + m15;   // + cg*16

    f32x4 c4[4][4];
#pragma unroll
    for (int r = 0; r < 4; ++r)
#pragma unroll
        for (int s = 0; s < 4; ++s) c4[r][s] = (f32x4){0.0f, 0.0f, 0.0f, 0.0f};

#pragma unroll
    for (int ks = 0; ks < 3; ++ks) {
        int kk = ks * 32 + quad * 8;
        bf16x8 bh[4], bl[4];
#pragma unroll
        for (int cg = 0; cg < 4; ++cg) {
            bh[cg] = load8(ah, brow + cg * 16, kk);
            bl[cg] = load8(al, brow + cg * 16, kk);
        }
#pragma unroll
        for (int rg = 0; rg < 4; ++rg) {
            bf16x8 xh = load8(ah, arow + rg * 16, kk);
            bf16x8 xl = load8(al, arow + rg * 16, kk);
#pragma unroll
            for (int cg = 0; cg < 4; ++cg) {
                c4[rg][cg] = __builtin_amdgcn_mfma_f32_16x16x32_bf16(xh, bh[cg], c4[rg][cg], 0, 0, 0);
                c4[rg][cg] = __builtin_amdgcn_mfma_f32_16x16x32_bf16(xh, bl[cg], c4[rg][cg], 0, 0, 0);
                c4[rg][cg] = __builtin_amdgcn_mfma_f32_16x16x32_bf16(xl, bh[cg], c4[rg][cg], 0, 0, 0);
            }
        }
    }

    // epilogue: C/D layout col=lane&15 (b-side), row=quad*4+reg (a-side)
    float4 pj[4];
    int jb = wx * 64 + m15;
#pragma unroll
    for (int cg = 0; cg < 4; ++cg) {
        int r = jb + cg * 16;
        pj[cg] = make_float4(prm[4][r], prm[5][r], prm[6][r], prm[7][r]);
    }
    float part = 0.0f;
    int ib = wy * 64 + quad * 4;
#pragma unroll
    for (int rg = 0; rg < 4; ++rg) {
#pragma unroll
        for (int e = 0; e < 4; ++e) {
            int r = ib + rg * 16 + e;
            float4 pi = make_float4(prm[0][r], prm[1][r], prm[2][r], prm[3][r]);
#pragma unroll
            for (int cg = 0; cg < 4; ++cg)
                part += c4[rg][cg][e] * kval(pi, pj[cg]);
        }
    }
    if (jt != it) part *= 2.0f;

    red[tid] = part;
    __syncthreads();
#pragma unroll
    for (int s = 128; s > 0; s >>= 1) {
        if (tid < s) red[tid] += red[tid + s];
        __syncthreads();
    }
    if (tid == 0) {
        atomicAdd(&acc[64 + b], red[0]);
        __threadfence();
        unsigned int o = atomicAdd((unsigned int*)(acc + 96), 1u);
        last = (o == NBLK - 1) ? 1 : 0;
    }
    __syncthreads();
    if (last && tid < 64) {
        float v = 0.0f;
        if (tid < BS) {
            float pq = atomicAdd(&acc[tid], 0.0f);        // coherent reads
            float pp = atomicAdd(&acc[32 + tid], 0.0f);
            float qq = atomicAdd(&acc[64 + tid], 0.0f);
            v = 2.0f * logf(pq) - logf(pp) - logf(qq);
        }
        v = wave_reduce_sum(v);
        if (tid == 0) out[0] = -v;
    }
}

extern "C" void kernel_launch(void* const* d_in, const int* in_sizes, int n_in,
                              void* d_out, int out_size, void* d_ws, size_t ws_size,
                              hipStream_t stream) {
    (void)in_sizes; (void)n_in; (void)out_size; (void)ws_size;
    const float* pred_bb  = (const float*)d_in[0];
    const float* pred_lab = (const float*)d_in[1];
    const float* gt_bb    = (const float*)d_in[2];
    const int*   gt_lab   = (const int*)d_in[3];
    float* out = (float*)d_out;

    unsigned short* ah = (unsigned short*)d_ws;            // 32000*96*2 B = 6.144 MB
    unsigned short* al = ah + (size_t)BS * KP * SK;        // 6.144 MB
    float* acc = (float*)(al + (size_t)BS * KP * SK);      // pq[32], pp[32], qq[32], cnt
    float* acc_pq = acc;
    float* acc_pp = acc + 32;

    hipLaunchKernelGGL(alpha_kernel, dim3(BS * KP / 4), dim3(256), 0, stream,
                       pred_lab, ah, al, acc);
    hipLaunchKernelGGL(ppq_kernel, dim3(5, BS), dim3(256), 0, stream,
                       pred_bb, ah, al, gt_bb, gt_lab, acc_pq, acc_pp);
    hipLaunchKernelGGL(qq_kernel, dim3(NBLK), dim3(256), 0, stream,
                       pred_bb, ah, al, acc, out);
}

// Round 4
// 129.522 us; speedup vs baseline: 1.4010x; 1.4010x over previous
//
#include <hip/hip_runtime.h>
#include <math.h>

#define BS 32
#define KP 1000
#define KPP 1024         // padded rows per image (zero rows 1000..1023)
#define KG 100
#define NC 80
#define SK 96            // bf16 K stride (80 + 16 zero pad)
#define LP 104           // LDS row stride in shorts (52 dwords; 52 mod 32 = 20 -> 8 bank-groups over 8 rows, conflict-free b128)
#define NT 8             // ceil(KP/128)
#define NPAIR 36         // NT*(NT+1)/2
#define NBLK (BS * NPAIR)

using bf16x8 = __attribute__((ext_vector_type(8))) short;
using f32x4  = __attribute__((ext_vector_type(4))) float;

__device__ __forceinline__ float wave_reduce_sum(float v) {
#pragma unroll
    for (int m = 32; m > 0; m >>= 1) v += __shfl_xor(v, m, 64);
    return v;
}
__device__ __forceinline__ float wave_reduce_max(float v) {
#pragma unroll
    for (int m = 32; m > 0; m >>= 1) v = fmaxf(v, __shfl_xor(v, m, 64));
    return v;
}

__device__ __forceinline__ unsigned short f2bf(float f) {   // RN-even
    unsigned int u = __float_as_uint(f);
    u += 0x7fffu + ((u >> 16) & 1u);
    return (unsigned short)(u >> 16);
}
__device__ __forceinline__ float bf2f(unsigned short h) {
    return __uint_as_float(((unsigned int)h) << 16);
}

// K_ij = N(m_i; m_j, v_i+v_j), diagonal 2-D. a,b = (mx, my, vx, vy)
__device__ __forceinline__ float kval(float4 a, float4 b) {
    float Sx = a.z + b.z, Sy = a.w + b.w;
    float ix = 1.0f / Sx, iy = 1.0f / Sy;
    float dx = a.x - b.x, dy = a.y - b.y;
    return 0.15915494309189535f * sqrtf(ix * iy) *
           __expf(-0.5f * (dx * dx * ix + dy * dy * iy));
}

// alpha[row][c] = sigmoid(l[80]) * softmax(l[0..79]) -> bf16, rows padded to
// 1024/image (pad rows zeroed). One wave per row. Block 0 zeroes acc[128].
__global__ __launch_bounds__(256) void alpha_kernel(const float* __restrict__ pl,
                                                    unsigned short* __restrict__ ah,
                                                    float* __restrict__ acc) {
    if (blockIdx.x == 0 && threadIdx.x < 128) acc[threadIdx.x] = 0.0f;
    int wave = threadIdx.x >> 6;
    int lane = threadIdx.x & 63;
    int rr = blockIdx.x * 4 + wave;                   // < BS*KPP = 32768
    int b = rr >> 10, r = rr & (KPP - 1);
    unsigned short* oh = ah + (size_t)rr * SK;
    if (r < KP) {
        const float* x = pl + ((size_t)b * KP + r) * (NC + 1);
        float l0 = x[lane];
        float l1 = (lane < 16) ? x[64 + lane] : -1e30f;
        float obj = x[NC];
        float m = wave_reduce_max(fmaxf(l0, l1));
        float e0 = __expf(l0 - m);
        float e1 = (lane < 16) ? __expf(l1 - m) : 0.0f;
        float s = wave_reduce_sum(e0 + e1);
        float sig = 1.0f / (1.0f + __expf(-obj));
        float sc = sig / s;
        oh[lane] = f2bf(e0 * sc);
        if (lane < 32) oh[64 + lane] = (lane < 16) ? f2bf(e1 * sc) : 0;
    } else {
        oh[lane] = 0;
        if (lane < 32) oh[64 + lane] = 0;
    }
}

// Fused pp + pq. grid (5, BS): blockIdx.x<4 -> pq chunk of 256 pred j's; ==4 -> pp.
__global__ __launch_bounds__(256) void ppq_kernel(const float* __restrict__ pb,
                                                  const unsigned short* __restrict__ ah,
                                                  const float* __restrict__ gtb,
                                                  const int* __restrict__ gtl,
                                                  float* __restrict__ acc_pq,
                                                  float* __restrict__ acc_pp) {
    __shared__ float4 gm[KG];
    __shared__ int gl[KG];
    __shared__ float red[256];
    int b = blockIdx.y;
    int tid = threadIdx.x;
    if (tid < KG) {
        float4 x = ((const float4*)gtb)[b * KG + tid];
        gm[tid] = make_float4(x.x, x.y, 0.25f * x.z * x.z, 0.25f * x.w * x.w);
        gl[tid] = gtl[b * KG + tid];
    }
    __syncthreads();
    float part = 0.0f;
    if (blockIdx.x < 4) {
        int j = blockIdx.x * 256 + tid;
        if (j < KP) {
            float4 x = ((const float4*)pb)[b * KP + j];
            float4 pm = make_float4(x.x, x.y, 0.25f * x.z * x.z, 0.25f * x.w * x.w);
            const unsigned short* rh = ah + ((size_t)(b << 10) + j) * SK;
#pragma unroll 4
            for (int i = 0; i < KG; ++i) {
                part += bf2f(rh[gl[i]]) * kval(gm[i], pm);
            }
        }
    } else {
        for (int p = tid; p < KG * KG; p += 256) {
            int i = p / KG;
            int j = p - i * KG;
            if (gl[i] == gl[j]) part += kval(gm[i], gm[j]);
        }
    }
    red[tid] = part;
    __syncthreads();
#pragma unroll
    for (int s = 128; s > 0; s >>= 1) {
        if (tid < s) red[tid] += red[tid + s];
        __syncthreads();
    }
    if (tid == 0) {
        if (blockIdx.x < 4) atomicAdd(&acc_pq[b], red[0]);
        else acc_pp[b] = red[0];
    }
}

// qq: per image, sum over 1000x1000 pred pairs, w = dot80(alpha_i, alpha_j).
// Single-pass bf16 MFMA Gram; 128x128 triangular tiles (off-diag x2).
// Tiles staged coalesced (contiguous 24.6 KB) -> padded LDS (conflict-free
// b128 fragment reads). b = bi&31 keeps each image on one XCD's L2.
// Last block (atomic counter) computes the final loss.
__global__ __launch_bounds__(256) void qq_kernel(const float* __restrict__ pb,
                                                 const unsigned short* __restrict__ ahg,
                                                 float* __restrict__ acc,
                                                 float* __restrict__ out) {
    __shared__ short la[128 * LP];
    __shared__ short lbb[128 * LP];
    __shared__ float prm[8][128];   // [0..3]=a-side mx,my,vx,vy ; [4..7]=b-side
    __shared__ float red[256];
    __shared__ int last;

    int bi = blockIdx.x;
    int b = bi & 31;                 // consecutive blocks -> same XCD residency per image
    int t = bi >> 5;                 // 0..35
    int it = 0, rem = t;
    while (rem >= NT - it) { rem -= NT - it; ++it; }
    int jt = it + rem;
    int i0 = it * 128, j0 = jt * 128;

    int tid = threadIdx.x;

    // stage per-row params (m, v) as SoA
    {
        int side = tid >> 7, r = tid & 127;
        int gi = (side ? j0 : i0) + r;
        float4 v = make_float4(0.0f, 0.0f, 1.0f, 1.0f);
        if (gi < KP) {
            float4 x = ((const float4*)pb)[b * KP + gi];
            v = make_float4(x.x, x.y, 0.25f * x.z * x.z, 0.25f * x.w * x.w);
        }
        prm[side * 4 + 0][r] = v.x;
        prm[side * 4 + 1][r] = v.y;
        prm[side * 4 + 2][r] = v.z;
        prm[side * 4 + 3][r] = v.w;
    }

    // stage alpha tiles: 128 rows x 96 bf16 = contiguous 24576 B per side.
    // float4 chunk o (0..1535): row = o/12, slot = o%12 -> LDS row*LP + slot*8.
    {
        const float4* sa = (const float4*)(ahg + ((size_t)(b << 10) + i0) * SK);
#pragma unroll
        for (int k = 0; k < 6; ++k) {
            int o = tid + k * 256;
            int row = o / 12, slot = o - row * 12;
            *(float4*)(la + row * LP + slot * 8) = sa[o];
        }
        if (jt != it) {
            const float4* sb = (const float4*)(ahg + ((size_t)(b << 10) + j0) * SK);
#pragma unroll
            for (int k = 0; k < 6; ++k) {
                int o = tid + k * 256;
                int row = o / 12, slot = o - row * 12;
                *(float4*)(lbb + row * LP + slot * 8) = sb[o];
            }
        }
    }
    __syncthreads();
    const short* LB = (jt != it) ? lbb : la;

    int lane = tid & 63, w = tid >> 6;
    int wy = w >> 1, wx = w & 1;
    int m15 = lane & 15, quad = lane >> 4;
    int ar = wy * 64 + m15;          // a-side LDS row (+ rg*16)
    int br = wx * 64 + m15;          // b-side LDS row (+ cg*16)

    f32x4 c4[4][4];
#pragma unroll
    for (int r = 0; r < 4; ++r)
#pragma unroll
        for (int s = 0; s < 4; ++s) c4[r][s] = (f32x4){0.0f, 0.0f, 0.0f, 0.0f};

#pragma unroll
    for (int ks = 0; ks < 3; ++ks) {
        int kk = ks * 32 + quad * 8;
        bf16x8 bh[4];
#pragma unroll
        for (int cg = 0; cg < 4; ++cg)
            bh[cg] = *(const bf16x8*)(LB + (br + cg * 16) * LP + kk);
#pragma unroll
        for (int rg = 0; rg < 4; ++rg) {
            bf16x8 xh = *(const bf16x8*)(la + (ar + rg * 16) * LP + kk);
#pragma unroll
            for (int cg = 0; cg < 4; ++cg)
                c4[rg][cg] = __builtin_amdgcn_mfma_f32_16x16x32_bf16(xh, bh[cg], c4[rg][cg], 0, 0, 0);
        }
    }

    // epilogue: C/D layout col=lane&15 (b-side), row=quad*4+reg (a-side)
    float4 pj[4];
    int jb = wx * 64 + m15;
#pragma unroll
    for (int cg = 0; cg < 4; ++cg) {
        int r = jb + cg * 16;
        pj[cg] = make_float4(prm[4][r], prm[5][r], prm[6][r], prm[7][r]);
    }
    float part = 0.0f;
    int ib = wy * 64 + quad * 4;
#pragma unroll
    for (int rg = 0; rg < 4; ++rg) {
#pragma unroll
        for (int e = 0; e < 4; ++e) {
            int r = ib + rg * 16 + e;
            float4 pi = make_float4(prm[0][r], prm[1][r], prm[2][r], prm[3][r]);
#pragma unroll
            for (int cg = 0; cg < 4; ++cg)
                part += c4[rg][cg][e] * kval(pi, pj[cg]);
        }
    }
    if (jt != it) part *= 2.0f;

    red[tid] = part;
    __syncthreads();
#pragma unroll
    for (int s = 128; s > 0; s >>= 1) {
        if (tid < s) red[tid] += red[tid + s];
        __syncthreads();
    }
    if (tid == 0) {
        atomicAdd(&acc[64 + b], red[0]);
        __threadfence();
        unsigned int o = atomicAdd((unsigned int*)(acc + 96), 1u);
        last = (o == NBLK - 1) ? 1 : 0;
    }
    __syncthreads();
    if (last && tid < 64) {
        float v = 0.0f;
        if (tid < BS) {
            float pq = atomicAdd(&acc[tid], 0.0f);        // coherent reads
            float pp = atomicAdd(&acc[32 + tid], 0.0f);
            float qq = atomicAdd(&acc[64 + tid], 0.0f);
            v = 2.0f * logf(pq) - logf(pp) - logf(qq);
        }
        v = wave_reduce_sum(v);
        if (tid == 0) out[0] = -v;
    }
}

extern "C" void kernel_launch(void* const* d_in, const int* in_sizes, int n_in,
                              void* d_out, int out_size, void* d_ws, size_t ws_size,
                              hipStream_t stream) {
    (void)in_sizes; (void)n_in; (void)out_size; (void)ws_size;
    const float* pred_bb  = (const float*)d_in[0];
    const float* pred_lab = (const float*)d_in[1];
    const float* gt_bb    = (const float*)d_in[2];
    const int*   gt_lab   = (const int*)d_in[3];
    float* out = (float*)d_out;

    unsigned short* ah = (unsigned short*)d_ws;            // 32768*96*2 B = 6.29 MB
    float* acc = (float*)(ah + (size_t)BS * KPP * SK);     // pq[32], pp[32], qq[32], cnt
    float* acc_pq = acc;
    float* acc_pp = acc + 32;

    hipLaunchKernelGGL(alpha_kernel, dim3(BS * KPP / 4), dim3(256), 0, stream,
                       pred_lab, ah, acc);
    hipLaunchKernelGGL(ppq_kernel, dim3(5, BS), dim3(256), 0, stream,
                       pred_bb, ah, gt_bb, gt_lab, acc_pq, acc_pp);
    hipLaunchKernelGGL(qq_kernel, dim3(NBLK), dim3(256), 0, stream,
                       pred_bb, ah, acc, out);
}

// Round 5
// 120.699 us; speedup vs baseline: 1.5035x; 1.0731x over previous
//
#include <hip/hip_runtime.h>
#include <math.h>

#define BS 32
#define KP 1000
#define KPP 1024         // padded rows per image (zero rows 1000..1023)
#define KG 100
#define NC 80
#define SK 96            // bf16 K stride (80 + 16 zero pad)
#define LP 104           // LDS row stride in shorts (52 dwords -> near-conflict-free b128)
#define NT 8             // ceil(KP/128)
#define NPAIR 36         // NT*(NT+1)/2
#define NBLK (BS * NPAIR)

using bf16x8 = __attribute__((ext_vector_type(8))) short;
using f32x4  = __attribute__((ext_vector_type(4))) float;

__device__ __forceinline__ float wave_reduce_sum(float v) {
#pragma unroll
    for (int m = 32; m > 0; m >>= 1) v += __shfl_xor(v, m, 64);
    return v;
}
__device__ __forceinline__ float wave_reduce_max(float v) {
#pragma unroll
    for (int m = 32; m > 0; m >>= 1) v = fmaxf(v, __shfl_xor(v, m, 64));
    return v;
}

__device__ __forceinline__ unsigned short f2bf(float f) {   // RN-even
    unsigned int u = __float_as_uint(f);
    u += 0x7fffu + ((u >> 16) & 1u);
    return (unsigned short)(u >> 16);
}
__device__ __forceinline__ float bf2f(unsigned short h) {
    return __uint_as_float(((unsigned int)h) << 16);
}

// K_ij = N(m_i; m_j, v_i+v_j), diagonal 2-D. a,b = (mx, my, vx, vy)
// dx^2/Sx + dy^2/Sy = (dx^2*Sy + dy^2*Sx) * rcp(Sx*Sy); sqrt(ix*iy) = rsq(Sx*Sy)
// -> 1 v_rcp + 1 v_rsq + 1 v_exp + ~11 VALU (vs 2 IEEE div sequences before).
__device__ __forceinline__ float kval(float4 a, float4 b) {
    float Sx = a.z + b.z, Sy = a.w + b.w;
    float dx = a.x - b.x, dy = a.y - b.y;
    float P  = Sx * Sy;
    float r  = __builtin_amdgcn_rcpf(P);
    float rs = __builtin_amdgcn_rsqf(P);
    float num = dx * dx * Sy + dy * dy * Sx;
    float q = num * r;
    return 0.15915494309189535f * rs * __expf(-0.5f * q);
}

// alpha[row][c] = sigmoid(l[80]) * softmax(l[0..79]) -> bf16, rows padded to
// 1024/image (pad rows zeroed). One wave per row. Block 0 zeroes acc[128].
__global__ __launch_bounds__(256) void alpha_kernel(const float* __restrict__ pl,
                                                    unsigned short* __restrict__ ah,
                                                    float* __restrict__ acc) {
    if (blockIdx.x == 0 && threadIdx.x < 128) acc[threadIdx.x] = 0.0f;
    int wave = threadIdx.x >> 6;
    int lane = threadIdx.x & 63;
    int rr = blockIdx.x * 4 + wave;                   // < BS*KPP = 32768
    int b = rr >> 10, r = rr & (KPP - 1);
    unsigned short* oh = ah + (size_t)rr * SK;
    if (r < KP) {
        const float* x = pl + ((size_t)b * KP + r) * (NC + 1);
        float l0 = x[lane];
        float l1 = (lane < 16) ? x[64 + lane] : -1e30f;
        float obj = x[NC];
        float m = wave_reduce_max(fmaxf(l0, l1));
        float e0 = __expf(l0 - m);
        float e1 = (lane < 16) ? __expf(l1 - m) : 0.0f;
        float s = wave_reduce_sum(e0 + e1);
        float sig = 1.0f / (1.0f + __expf(-obj));
        float sc = sig / s;
        oh[lane] = f2bf(e0 * sc);
        if (lane < 32) oh[64 + lane] = (lane < 16) ? f2bf(e1 * sc) : 0;
    } else {
        oh[lane] = 0;
        if (lane < 32) oh[64 + lane] = 0;
    }
}

// Fused pp + pq. grid (5, BS): blockIdx.x<4 -> pq chunk of 256 pred j's; ==4 -> pp.
__global__ __launch_bounds__(256) void ppq_kernel(const float* __restrict__ pb,
                                                  const unsigned short* __restrict__ ah,
                                                  const float* __restrict__ gtb,
                                                  const int* __restrict__ gtl,
                                                  float* __restrict__ acc_pq,
                                                  float* __restrict__ acc_pp) {
    __shared__ float4 gm[KG];
    __shared__ int gl[KG];
    __shared__ float red[4];
    int b = blockIdx.y;
    int tid = threadIdx.x;
    if (tid < KG) {
        float4 x = ((const float4*)gtb)[b * KG + tid];
        gm[tid] = make_float4(x.x, x.y, 0.25f * x.z * x.z, 0.25f * x.w * x.w);
        gl[tid] = gtl[b * KG + tid];
    }
    __syncthreads();
    float part = 0.0f;
    if (blockIdx.x < 4) {
        int j = blockIdx.x * 256 + tid;
        if (j < KP) {
            float4 x = ((const float4*)pb)[b * KP + j];
            float4 pm = make_float4(x.x, x.y, 0.25f * x.z * x.z, 0.25f * x.w * x.w);
            const unsigned short* rh = ah + ((size_t)(b << 10) + j) * SK;
#pragma unroll 4
            for (int i = 0; i < KG; ++i) {
                part += bf2f(rh[gl[i]]) * kval(gm[i], pm);
            }
        }
    } else {
        for (int p = tid; p < KG * KG; p += 256) {
            int i = p / KG;
            int j = p - i * KG;
            if (gl[i] == gl[j]) part += kval(gm[i], gm[j]);
        }
    }
    part = wave_reduce_sum(part);
    int lane = tid & 63, w = tid >> 6;
    if (lane == 0) red[w] = part;
    __syncthreads();
    if (tid == 0) {
        float s = red[0] + red[1] + red[2] + red[3];
        if (blockIdx.x < 4) atomicAdd(&acc_pq[b], s);
        else acc_pp[b] = s;
    }
}

// qq: per image, sum over 1000x1000 pred pairs, w = dot80(alpha_i, alpha_j).
// Single-pass bf16 MFMA Gram; 128x128 triangular tiles (off-diag x2).
// Tiles staged coalesced -> padded LDS; b = bi&31 keeps each image on one XCD.
// Last block (atomic counter) computes the final loss.
__global__ __launch_bounds__(256) void qq_kernel(const float* __restrict__ pb,
                                                 const unsigned short* __restrict__ ahg,
                                                 float* __restrict__ acc,
                                                 float* __restrict__ out) {
    __shared__ short la[128 * LP];
    __shared__ short lbb[128 * LP];
    __shared__ float prm[8][128];   // [0..3]=a-side mx,my,vx,vy ; [4..7]=b-side
    __shared__ float red[4];
    __shared__ int last;

    int bi = blockIdx.x;
    int b = bi & 31;                 // consecutive blocks -> same XCD residency per image
    int t = bi >> 5;                 // 0..35
    int it = 0, rem = t;
    while (rem >= NT - it) { rem -= NT - it; ++it; }
    int jt = it + rem;
    int i0 = it * 128, j0 = jt * 128;

    int tid = threadIdx.x;

    // stage per-row params (m, v) as SoA
    {
        int side = tid >> 7, r = tid & 127;
        int gi = (side ? j0 : i0) + r;
        float4 v = make_float4(0.0f, 0.0f, 1.0f, 1.0f);
        if (gi < KP) {
            float4 x = ((const float4*)pb)[b * KP + gi];
            v = make_float4(x.x, x.y, 0.25f * x.z * x.z, 0.25f * x.w * x.w);
        }
        prm[side * 4 + 0][r] = v.x;
        prm[side * 4 + 1][r] = v.y;
        prm[side * 4 + 2][r] = v.z;
        prm[side * 4 + 3][r] = v.w;
    }

    // stage alpha tiles: 128 rows x 96 bf16 = contiguous 24576 B per side.
    {
        const float4* sa = (const float4*)(ahg + ((size_t)(b << 10) + i0) * SK);
#pragma unroll
        for (int k = 0; k < 6; ++k) {
            int o = tid + k * 256;
            int row = o / 12, slot = o - row * 12;
            *(float4*)(la + row * LP + slot * 8) = sa[o];
        }
        if (jt != it) {
            const float4* sb = (const float4*)(ahg + ((size_t)(b << 10) + j0) * SK);
#pragma unroll
            for (int k = 0; k < 6; ++k) {
                int o = tid + k * 256;
                int row = o / 12, slot = o - row * 12;
                *(float4*)(lbb + row * LP + slot * 8) = sb[o];
            }
        }
    }
    __syncthreads();
    const short* LB = (jt != it) ? lbb : la;

    int lane = tid & 63, w = tid >> 6;
    int wy = w >> 1, wx = w & 1;
    int m15 = lane & 15, quad = lane >> 4;
    int ar = wy * 64 + m15;          // a-side LDS row (+ rg*16)
    int br = wx * 64 + m15;          // b-side LDS row (+ cg*16)

    f32x4 c4[4][4];
#pragma unroll
    for (int r = 0; r < 4; ++r)
#pragma unroll
        for (int s = 0; s < 4; ++s) c4[r][s] = (f32x4){0.0f, 0.0f, 0.0f, 0.0f};

#pragma unroll
    for (int ks = 0; ks < 3; ++ks) {
        int kk = ks * 32 + quad * 8;
        bf16x8 bh[4];
#pragma unroll
        for (int cg = 0; cg < 4; ++cg)
            bh[cg] = *(const bf16x8*)(LB + (br + cg * 16) * LP + kk);
#pragma unroll
        for (int rg = 0; rg < 4; ++rg) {
            bf16x8 xh = *(const bf16x8*)(la + (ar + rg * 16) * LP + kk);
#pragma unroll
            for (int cg = 0; cg < 4; ++cg)
                c4[rg][cg] = __builtin_amdgcn_mfma_f32_16x16x32_bf16(xh, bh[cg], c4[rg][cg], 0, 0, 0);
        }
    }

    // epilogue: C/D layout col=lane&15 (b-side), row=quad*4+reg (a-side)
    float4 pj[4];
    int jb = wx * 64 + m15;
#pragma unroll
    for (int cg = 0; cg < 4; ++cg) {
        int r = jb + cg * 16;
        pj[cg] = make_float4(prm[4][r], prm[5][r], prm[6][r], prm[7][r]);
    }
    float part = 0.0f;
    int ib = wy * 64 + quad * 4;
#pragma unroll
    for (int rg = 0; rg < 4; ++rg) {
#pragma unroll
        for (int e = 0; e < 4; ++e) {
            int r = ib + rg * 16 + e;
            float4 pi = make_float4(prm[0][r], prm[1][r], prm[2][r], prm[3][r]);
#pragma unroll
            for (int cg = 0; cg < 4; ++cg)
                part += c4[rg][cg][e] * kval(pi, pj[cg]);
        }
    }
    if (jt != it) part *= 2.0f;

    part = wave_reduce_sum(part);
    if (lane == 0) red[w] = part;
    __syncthreads();
    if (tid == 0) {
        atomicAdd(&acc[64 + b], red[0] + red[1] + red[2] + red[3]);
        __threadfence();
        unsigned int o = atomicAdd((unsigned int*)(acc + 96), 1u);
        last = (o == NBLK - 1) ? 1 : 0;
    }
    __syncthreads();
    if (last && tid < 64) {
        float v = 0.0f;
        if (tid < BS) {
            float pq = atomicAdd(&acc[tid], 0.0f);        // coherent reads
            float pp = atomicAdd(&acc[32 + tid], 0.0f);
            float qq = atomicAdd(&acc[64 + tid], 0.0f);
            v = 2.0f * logf(pq) - logf(pp) - logf(qq);
        }
        v = wave_reduce_sum(v);
        if (tid == 0) out[0] = -v;
    }
}

extern "C" void kernel_launch(void* const* d_in, const int* in_sizes, int n_in,
                              void* d_out, int out_size, void* d_ws, size_t ws_size,
                              hipStream_t stream) {
    (void)in_sizes; (void)n_in; (void)out_size; (void)ws_size;
    const float* pred_bb  = (const float*)d_in[0];
    const float* pred_lab = (const float*)d_in[1];
    const float* gt_bb    = (const float*)d_in[2];
    const int*   gt_lab   = (const int*)d_in[3];
    float* out = (float*)d_out;

    unsigned short* ah = (unsigned short*)d_ws;            // 32768*96*2 B = 6.29 MB
    float* acc = (float*)(ah + (size_t)BS * KPP * SK);     // pq[32], pp[32], qq[32], cnt
    float* acc_pq = acc;
    float* acc_pp = acc + 32;

    hipLaunchKernelGGL(alpha_kernel, dim3(BS * KPP / 4), dim3(256), 0, stream,
                       pred_lab, ah, acc);
    hipLaunchKernelGGL(ppq_kernel, dim3(5, BS), dim3(256), 0, stream,
                       pred_bb, ah, gt_bb, gt_lab, acc_pq, acc_pp);
    hipLaunchKernelGGL(qq_kernel, dim3(NBLK), dim3(256), 0, stream,
                       pred_bb, ah, acc, out);
}

// Round 6
// 116.912 us; speedup vs baseline: 1.5522x; 1.0324x over previous
//
#include <hip/hip_runtime.h>
#include <math.h>

#define BS 32
#define KP 1000
#define KPP 1024         // padded rows per image (zero rows 1000..1023)
#define KG 100
#define NC 80
#define SK 96            // bf16 K stride (80 + 16 zero pad)
#define LP 104           // LDS row stride in shorts; shorts 96..103 hold the row's (mx,my,vx,vy) float4
#define NT 8             // ceil(KP/128)
#define NPAIR 36         // NT*(NT+1)/2
#define NBLK (BS * NPAIR)

using bf16x8 = __attribute__((ext_vector_type(8))) short;
using f32x4  = __attribute__((ext_vector_type(4))) float;

__device__ __forceinline__ float wave_reduce_sum(float v) {
#pragma unroll
    for (int m = 32; m > 0; m >>= 1) v += __shfl_xor(v, m, 64);
    return v;
}
__device__ __forceinline__ float wave_reduce_max(float v) {
#pragma unroll
    for (int m = 32; m > 0; m >>= 1) v = fmaxf(v, __shfl_xor(v, m, 64));
    return v;
}

__device__ __forceinline__ unsigned short f2bf(float f) {   // RN-even
    unsigned int u = __float_as_uint(f);
    u += 0x7fffu + ((u >> 16) & 1u);
    return (unsigned short)(u >> 16);
}
__device__ __forceinline__ float bf2f(unsigned short h) {
    return __uint_as_float(((unsigned int)h) << 16);
}

// K_ij = N(m_i; m_j, v_i+v_j), diagonal 2-D. a,b = (mx, my, vx, vy)
// dx^2/Sx + dy^2/Sy = (dx^2*Sy + dy^2*Sx) * rcp(Sx*Sy); sqrt(ix*iy) = rsq(Sx*Sy)
__device__ __forceinline__ float kval(float4 a, float4 b) {
    float Sx = a.z + b.z, Sy = a.w + b.w;
    float dx = a.x - b.x, dy = a.y - b.y;
    float P  = Sx * Sy;
    float r  = __builtin_amdgcn_rcpf(P);
    float rs = __builtin_amdgcn_rsqf(P);
    float num = dx * dx * Sy + dy * dy * Sx;
    float q = num * r;
    return 0.15915494309189535f * rs * __expf(-0.5f * q);
}

// alpha[row][c] = sigmoid(l[80]) * softmax(l[0..79]) -> bf16, rows padded to
// 1024/image (pad rows zeroed). One wave per row. Block 0 zeroes acc[128].
__global__ __launch_bounds__(256) void alpha_kernel(const float* __restrict__ pl,
                                                    unsigned short* __restrict__ ah,
                                                    float* __restrict__ acc) {
    if (blockIdx.x == 0 && threadIdx.x < 128) acc[threadIdx.x] = 0.0f;
    int wave = threadIdx.x >> 6;
    int lane = threadIdx.x & 63;
    int rr = blockIdx.x * 4 + wave;                   // < BS*KPP = 32768
    int b = rr >> 10, r = rr & (KPP - 1);
    unsigned short* oh = ah + (size_t)rr * SK;
    if (r < KP) {
        const float* x = pl + ((size_t)b * KP + r) * (NC + 1);
        float l0 = x[lane];
        float l1 = (lane < 16) ? x[64 + lane] : -1e30f;
        float obj = x[NC];
        float m = wave_reduce_max(fmaxf(l0, l1));
        float e0 = __expf(l0 - m);
        float e1 = (lane < 16) ? __expf(l1 - m) : 0.0f;
        float s = wave_reduce_sum(e0 + e1);
        float sig = 1.0f / (1.0f + __expf(-obj));
        float sc = sig / s;
        oh[lane] = f2bf(e0 * sc);
        if (lane < 32) oh[64 + lane] = (lane < 16) ? f2bf(e1 * sc) : 0;
    } else {
        oh[lane] = 0;
        if (lane < 32) oh[64 + lane] = 0;
    }
}

// Fused pp + pq. grid (5, BS): blockIdx.x<4 -> pq chunk of 256 pred j's; ==4 -> pp.
__global__ __launch_bounds__(256) void ppq_kernel(const float* __restrict__ pb,
                                                  const unsigned short* __restrict__ ah,
                                                  const float* __restrict__ gtb,
                                                  const int* __restrict__ gtl,
                                                  float* __restrict__ acc_pq,
                                                  float* __restrict__ acc_pp) {
    __shared__ float4 gm[KG];
    __shared__ int gl[KG];
    __shared__ float red[4];
    int b = blockIdx.y;
    int tid = threadIdx.x;
    if (tid < KG) {
        float4 x = ((const float4*)gtb)[b * KG + tid];
        gm[tid] = make_float4(x.x, x.y, 0.25f * x.z * x.z, 0.25f * x.w * x.w);
        gl[tid] = gtl[b * KG + tid];
    }
    __syncthreads();
    float part = 0.0f;
    if (blockIdx.x < 4) {
        int j = blockIdx.x * 256 + tid;
        if (j < KP) {
            float4 x = ((const float4*)pb)[b * KP + j];
            float4 pm = make_float4(x.x, x.y, 0.25f * x.z * x.z, 0.25f * x.w * x.w);
            const unsigned short* rh = ah + ((size_t)(b << 10) + j) * SK;
#pragma unroll 4
            for (int i = 0; i < KG; ++i) {
                part += bf2f(rh[gl[i]]) * kval(gm[i], pm);
            }
        }
    } else {
        for (int p = tid; p < KG * KG; p += 256) {
            int i = p / KG;
            int j = p - i * KG;
            if (gl[i] == gl[j]) part += kval(gm[i], gm[j]);
        }
    }
    part = wave_reduce_sum(part);
    int lane = tid & 63, w = tid >> 6;
    if (lane == 0) red[w] = part;
    __syncthreads();
    if (tid == 0) {
        float s = red[0] + red[1] + red[2] + red[3];
        if (blockIdx.x < 4) atomicAdd(&acc_pq[b], s);
        else acc_pp[b] = s;
    }
}

// qq: per image, sum over 1000x1000 pred pairs, w = dot80(alpha_i, alpha_j).
// Single-pass bf16 MFMA Gram; 128x128 triangular tiles (off-diag x2).
// Row params (mx,my,vx,vy) live in the 16 B hole at the end of each LDS row
// (a-side in la, b-side in lbb) -> 53.3 KB LDS -> 3 blocks/CU.
// Last block (atomic counter) computes the final loss.
__global__ __launch_bounds__(256, 3) void qq_kernel(const float* __restrict__ pb,
                                                    const unsigned short* __restrict__ ahg,
                                                    float* __restrict__ acc,
                                                    float* __restrict__ out) {
    __shared__ short la[128 * LP];
    __shared__ short lbb[128 * LP];
    __shared__ float red[4];
    __shared__ int last;

    int bi = blockIdx.x;
    int b = bi & 31;                 // consecutive blocks -> same XCD residency per image
    int t = bi >> 5;                 // 0..35
    int it = 0, rem = t;
    while (rem >= NT - it) { rem -= NT - it; ++it; }
    int jt = it + rem;
    int i0 = it * 128, j0 = jt * 128;

    int tid = threadIdx.x;

    // stage per-row params into the row holes (a-side -> la, b-side -> lbb)
    {
        int side = tid >> 7, r = tid & 127;
        int gi = (side ? j0 : i0) + r;
        float4 v = make_float4(0.0f, 0.0f, 1.0f, 1.0f);
        if (gi < KP) {
            float4 x = ((const float4*)pb)[b * KP + gi];
            v = make_float4(x.x, x.y, 0.25f * x.z * x.z, 0.25f * x.w * x.w);
        }
        short* L = side ? lbb : la;
        *(float4*)(L + r * LP + 96) = v;
    }

    // stage alpha tiles: 128 rows x 96 bf16 = contiguous 24576 B per side.
    {
        const float4* sa = (const float4*)(ahg + ((size_t)(b << 10) + i0) * SK);
#pragma unroll
        for (int k = 0; k < 6; ++k) {
            int o = tid + k * 256;
            int row = o / 12, slot = o - row * 12;
            *(float4*)(la + row * LP + slot * 8) = sa[o];
        }
        if (jt != it) {
            const float4* sb = (const float4*)(ahg + ((size_t)(b << 10) + j0) * SK);
#pragma unroll
            for (int k = 0; k < 6; ++k) {
                int o = tid + k * 256;
                int row = o / 12, slot = o - row * 12;
                *(float4*)(lbb + row * LP + slot * 8) = sb[o];
            }
        }
    }
    __syncthreads();
    const short* LB = (jt != it) ? lbb : la;

    int lane = tid & 63, w = tid >> 6;
    int wy = w >> 1, wx = w & 1;
    int m15 = lane & 15, quad = lane >> 4;
    int ar = wy * 64 + m15;          // a-side LDS row (+ rg*16)
    int br = wx * 64 + m15;          // b-side LDS row (+ cg*16)

    f32x4 c4[4][4];
#pragma unroll
    for (int r = 0; r < 4; ++r)
#pragma unroll
        for (int s = 0; s < 4; ++s) c4[r][s] = (f32x4){0.0f, 0.0f, 0.0f, 0.0f};

#pragma unroll
    for (int ks = 0; ks < 3; ++ks) {
        int kk = ks * 32 + quad * 8;
        bf16x8 bh[4];
#pragma unroll
        for (int cg = 0; cg < 4; ++cg)
            bh[cg] = *(const bf16x8*)(LB + (br + cg * 16) * LP + kk);
#pragma unroll
        for (int rg = 0; rg < 4; ++rg) {
            bf16x8 xh = *(const bf16x8*)(la + (ar + rg * 16) * LP + kk);
#pragma unroll
            for (int cg = 0; cg < 4; ++cg)
                c4[rg][cg] = __builtin_amdgcn_mfma_f32_16x16x32_bf16(xh, bh[cg], c4[rg][cg], 0, 0, 0);
        }
    }

    // epilogue: C/D layout col=lane&15 (b-side), row=quad*4+reg (a-side)
    float4 pj[4];
    int jb = wx * 64 + m15;
#pragma unroll
    for (int cg = 0; cg < 4; ++cg)
        pj[cg] = *(const float4*)(lbb + (jb + cg * 16) * LP + 96);
    float part = 0.0f;
    int ib = wy * 64 + quad * 4;
#pragma unroll
    for (int rg = 0; rg < 4; ++rg) {
#pragma unroll
        for (int e = 0; e < 4; ++e) {
            float4 pi = *(const float4*)(la + (ib + rg * 16 + e) * LP + 96);
#pragma unroll
            for (int cg = 0; cg < 4; ++cg)
                part += c4[rg][cg][e] * kval(pi, pj[cg]);
        }
    }
    if (jt != it) part *= 2.0f;

    part = wave_reduce_sum(part);
    if (lane == 0) red[w] = part;
    __syncthreads();
    if (tid == 0) {
        atomicAdd(&acc[64 + b], red[0] + red[1] + red[2] + red[3]);
        __threadfence();
        unsigned int o = atomicAdd((unsigned int*)(acc + 96), 1u);
        last = (o == NBLK - 1) ? 1 : 0;
    }
    __syncthreads();
    if (last && tid < 64) {
        float v = 0.0f;
        if (tid < BS) {
            float pq = atomicAdd(&acc[tid], 0.0f);        // coherent reads
            float pp = atomicAdd(&acc[32 + tid], 0.0f);
            float qq = atomicAdd(&acc[64 + tid], 0.0f);
            v = 2.0f * logf(pq) - logf(pp) - logf(qq);
        }
        v = wave_reduce_sum(v);
        if (tid == 0) out[0] = -v;
    }
}

extern "C" void kernel_launch(void* const* d_in, const int* in_sizes, int n_in,
                              void* d_out, int out_size, void* d_ws, size_t ws_size,
                              hipStream_t stream) {
    (void)in_sizes; (void)n_in; (void)out_size; (void)ws_size;
    const float* pred_bb  = (const float*)d_in[0];
    const float* pred_lab = (const float*)d_in[1];
    const float* gt_bb    = (const float*)d_in[2];
    const int*   gt_lab   = (const int*)d_in[3];
    float* out = (float*)d_out;

    unsigned short* ah = (unsigned short*)d_ws;            // 32768*96*2 B = 6.29 MB
    float* acc = (float*)(ah + (size_t)BS * KPP * SK);     // pq[32], pp[32], qq[32], cnt
    float* acc_pq = acc;
    float* acc_pp = acc + 32;

    hipLaunchKernelGGL(alpha_kernel, dim3(BS * KPP / 4), dim3(256), 0, stream,
                       pred_lab, ah, acc);
    hipLaunchKernelGGL(ppq_kernel, dim3(5, BS), dim3(256), 0, stream,
                       pred_bb, ah, gt_bb, gt_lab, acc_pq, acc_pp);
    hipLaunchKernelGGL(qq_kernel, dim3(NBLK), dim3(256), 0, stream,
                       pred_bb, ah, acc, out);
}

// Round 7
// 106.270 us; speedup vs baseline: 1.7076x; 1.1001x over previous
//
#include <hip/hip_runtime.h>
#include <math.h>

#define BS 32
#define KP 1000
#define KPP 1024         // padded rows per image (zero rows 1000..1023)
#define KG 100
#define NC 80
#define SK 96            // bf16 K stride (80 + 16 zero pad)
#define LP 104           // LDS row stride in shorts; shorts 96..103 hold the row's (mx,my,vx,vy) float4
#define NT 8             // ceil(KP/128)
#define NPAIR 36         // NT*(NT+1)/2
#define NQQ (BS * NPAIR) // 1152 qq tile blocks
#define NPPQ (5 * BS)    // 160 pp/pq blocks (ride along in the same dispatch)
#define NALL (NQQ + NPPQ)

using bf16x8 = __attribute__((ext_vector_type(8))) short;
using f32x4  = __attribute__((ext_vector_type(4))) float;
using f32x2  = __attribute__((ext_vector_type(2))) float;

__device__ __forceinline__ float wave_reduce_sum(float v) {
#pragma unroll
    for (int m = 32; m > 0; m >>= 1) v += __shfl_xor(v, m, 64);
    return v;
}
__device__ __forceinline__ float wave_reduce_max(float v) {
#pragma unroll
    for (int m = 32; m > 0; m >>= 1) v = fmaxf(v, __shfl_xor(v, m, 64));
    return v;
}

__device__ __forceinline__ unsigned short f2bf(float f) {   // RN-even
    unsigned int u = __float_as_uint(f);
    u += 0x7fffu + ((u >> 16) & 1u);
    return (unsigned short)(u >> 16);
}
__device__ __forceinline__ float bf2f(unsigned short h) {
    return __uint_as_float(((unsigned int)h) << 16);
}

// K_ij = N(m_i; m_j, v_i+v_j), diagonal 2-D. a,b = (mx, my, vx, vy)
// x/y dims as packed f32 pairs (v_pk_*); rcp(P) folded to rsq(P)^2 ->
// 2 transcendentals (rsq, exp) + ~9 VALU per kval.
__device__ __forceinline__ float kval(float4 a, float4 b) {
    f32x2 S = (f32x2){a.z, a.w} + (f32x2){b.z, b.w};
    f32x2 d = (f32x2){a.x, a.y} - (f32x2){b.x, b.y};
    f32x2 d2 = d * d;
    f32x2 t = d2 * S.yx;                 // dx^2*Sy , dy^2*Sx
    float num = t.x + t.y;
    float P = S.x * S.y;
    float rs = __builtin_amdgcn_rsqf(P);
    float q = num * rs * rs;             // num * rcp(P)
    return 0.15915494309189535f * rs * __expf(-0.5f * q);
}

// alpha[row][c] = sigmoid(l[80]) * softmax(l[0..79]) -> bf16, rows padded to
// 1024/image (pad rows zeroed). One wave per row. Block 0 zeroes acc[128].
__global__ __launch_bounds__(256) void alpha_kernel(const float* __restrict__ pl,
                                                    unsigned short* __restrict__ ah,
                                                    float* __restrict__ acc) {
    if (blockIdx.x == 0 && threadIdx.x < 128) acc[threadIdx.x] = 0.0f;
    int wave = threadIdx.x >> 6;
    int lane = threadIdx.x & 63;
    int rr = blockIdx.x * 4 + wave;                   // < BS*KPP = 32768
    int b = rr >> 10, r = rr & (KPP - 1);
    unsigned short* oh = ah + (size_t)rr * SK;
    if (r < KP) {
        const float* x = pl + ((size_t)b * KP + r) * (NC + 1);
        float l0 = x[lane];
        float l1 = (lane < 16) ? x[64 + lane] : -1e30f;
        float obj = x[NC];
        float m = wave_reduce_max(fmaxf(l0, l1));
        float e0 = __expf(l0 - m);
        float e1 = (lane < 16) ? __expf(l1 - m) : 0.0f;
        float s = wave_reduce_sum(e0 + e1);
        float sig = 1.0f / (1.0f + __expf(-obj));
        float sc = sig / s;
        oh[lane] = f2bf(e0 * sc);
        if (lane < 32) oh[64 + lane] = (lane < 16) ? f2bf(e1 * sc) : 0;
    } else {
        oh[lane] = 0;
        if (lane < 32) oh[64 + lane] = 0;
    }
}

// Single main dispatch: blocks [0,NPPQ) do pp/pq; blocks [NPPQ,NALL) do qq
// 128x128 MFMA Gram tiles (triangular, off-diag x2). Row params live in the
// 16 B hole of each LDS row -> 53.2 KB LDS -> 3 blocks/CU. The last of all
// NALL blocks (atomic counter) computes the final loss.
__global__ __launch_bounds__(256, 3) void main_kernel(const float* __restrict__ pb,
                                                      const unsigned short* __restrict__ ahg,
                                                      const float* __restrict__ gtb,
                                                      const int* __restrict__ gtl,
                                                      float* __restrict__ acc,
                                                      float* __restrict__ out) {
    __shared__ short la[128 * LP];
    __shared__ short lbb[128 * LP];
    __shared__ float red[4];
    __shared__ int last;

    int tid = threadIdx.x;
    int lane = tid & 63, w = tid >> 6;
    int bi = blockIdx.x;

    if (bi < NPPQ) {
        // ---------------- pp / pq path ----------------
        int b = bi & 31;
        int p5 = bi >> 5;                // 0..3 = pq chunks, 4 = pp
        float4* gm = (float4*)lbb;       // 1600 B alias
        int* gl = (int*)la;              // 400 B alias
        if (tid < KG) {
            float4 x = ((const float4*)gtb)[b * KG + tid];
            gm[tid] = make_float4(x.x, x.y, 0.25f * x.z * x.z, 0.25f * x.w * x.w);
            gl[tid] = gtl[b * KG + tid];
        }
        __syncthreads();
        float part = 0.0f;
        if (p5 < 4) {
            int j = p5 * 256 + tid;
            if (j < KP) {
                float4 x = ((const float4*)pb)[b * KP + j];
                float4 pm = make_float4(x.x, x.y, 0.25f * x.z * x.z, 0.25f * x.w * x.w);
                const unsigned short* rh = ahg + ((size_t)(b << 10) + j) * SK;
#pragma unroll 4
                for (int i = 0; i < KG; ++i) {
                    part += bf2f(rh[gl[i]]) * kval(gm[i], pm);
                }
            }
        } else {
            for (int p = tid; p < KG * KG; p += 256) {
                int i = p / KG;
                int j = p - i * KG;
                if (gl[i] == gl[j]) part += kval(gm[i], gm[j]);
            }
        }
        part = wave_reduce_sum(part);
        if (lane == 0) red[w] = part;
        __syncthreads();
        if (tid == 0) {
            float s = red[0] + red[1] + red[2] + red[3];
            atomicAdd((p5 < 4) ? &acc[b] : &acc[32 + b], s);
        }
    } else {
        // ---------------- qq path ----------------
        int qi = bi - NPPQ;
        int b = qi & 31;                 // consecutive blocks -> same XCD per image
        int t = qi >> 5;                 // 0..35
        int it = 0, rem = t;
        while (rem >= NT - it) { rem -= NT - it; ++it; }
        int jt = it + rem;
        int i0 = it * 128, j0 = jt * 128;

        // per-row params into the row holes (a-side -> la, b-side -> lbb)
        {
            int side = tid >> 7, r = tid & 127;
            int gi = (side ? j0 : i0) + r;
            float4 v = make_float4(0.0f, 0.0f, 1.0f, 1.0f);
            if (gi < KP) {
                float4 x = ((const float4*)pb)[b * KP + gi];
                v = make_float4(x.x, x.y, 0.25f * x.z * x.z, 0.25f * x.w * x.w);
            }
            short* L = side ? lbb : la;
            *(float4*)(L + r * LP + 96) = v;
        }

        // stage alpha tiles: 128 rows x 96 bf16 = contiguous 24576 B per side
        {
            const float4* sa = (const float4*)(ahg + ((size_t)(b << 10) + i0) * SK);
#pragma unroll
            for (int k = 0; k < 6; ++k) {
                int o = tid + k * 256;
                int row = o / 12, slot = o - row * 12;
                *(float4*)(la + row * LP + slot * 8) = sa[o];
            }
            if (jt != it) {
                const float4* sb = (const float4*)(ahg + ((size_t)(b << 10) + j0) * SK);
#pragma unroll
                for (int k = 0; k < 6; ++k) {
                    int o = tid + k * 256;
                    int row = o / 12, slot = o - row * 12;
                    *(float4*)(lbb + row * LP + slot * 8) = sb[o];
                }
            }
        }
        __syncthreads();
        const short* LB = (jt != it) ? lbb : la;

        int wy = w >> 1, wx = w & 1;
        int m15 = lane & 15, quad = lane >> 4;
        int ar = wy * 64 + m15;
        int br = wx * 64 + m15;

        f32x4 c4[4][4];
#pragma unroll
        for (int r = 0; r < 4; ++r)
#pragma unroll
            for (int s = 0; s < 4; ++s) c4[r][s] = (f32x4){0.0f, 0.0f, 0.0f, 0.0f};

#pragma unroll
        for (int ks = 0; ks < 3; ++ks) {
            int kk = ks * 32 + quad * 8;
            bf16x8 bh[4];
#pragma unroll
            for (int cg = 0; cg < 4; ++cg)
                bh[cg] = *(const bf16x8*)(LB + (br + cg * 16) * LP + kk);
#pragma unroll
            for (int rg = 0; rg < 4; ++rg) {
                bf16x8 xh = *(const bf16x8*)(la + (ar + rg * 16) * LP + kk);
#pragma unroll
                for (int cg = 0; cg < 4; ++cg)
                    c4[rg][cg] = __builtin_amdgcn_mfma_f32_16x16x32_bf16(xh, bh[cg], c4[rg][cg], 0, 0, 0);
            }
        }

        // epilogue: C/D layout col=lane&15 (b-side), row=quad*4+reg (a-side)
        float4 pj[4];
        int jb = wx * 64 + m15;
#pragma unroll
        for (int cg = 0; cg < 4; ++cg)
            pj[cg] = *(const float4*)(lbb + (jb + cg * 16) * LP + 96);
        float part = 0.0f;
        int ib = wy * 64 + quad * 4;
#pragma unroll
        for (int rg = 0; rg < 4; ++rg) {
#pragma unroll
            for (int e = 0; e < 4; ++e) {
                float4 pi = *(const float4*)(la + (ib + rg * 16 + e) * LP + 96);
#pragma unroll
                for (int cg = 0; cg < 4; ++cg)
                    part += c4[rg][cg][e] * kval(pi, pj[cg]);
            }
        }
        if (jt != it) part *= 2.0f;

        part = wave_reduce_sum(part);
        if (lane == 0) red[w] = part;
        __syncthreads();
        if (tid == 0)
            atomicAdd(&acc[64 + b], red[0] + red[1] + red[2] + red[3]);
    }

    // ---------------- common finalize ----------------
    if (tid == 0) {
        __threadfence();
        unsigned int o = atomicAdd((unsigned int*)(acc + 96), 1u);
        last = (o == NALL - 1) ? 1 : 0;
    }
    __syncthreads();
    if (last && tid < 64) {
        float v = 0.0f;
        if (tid < BS) {
            float pq = atomicAdd(&acc[tid], 0.0f);        // coherent reads
            float pp = atomicAdd(&acc[32 + tid], 0.0f);
            float qq = atomicAdd(&acc[64 + tid], 0.0f);
            v = 2.0f * logf(pq) - logf(pp) - logf(qq);
        }
        v = wave_reduce_sum(v);
        if (tid == 0) out[0] = -v;
    }
}

extern "C" void kernel_launch(void* const* d_in, const int* in_sizes, int n_in,
                              void* d_out, int out_size, void* d_ws, size_t ws_size,
                              hipStream_t stream) {
    (void)in_sizes; (void)n_in; (void)out_size; (void)ws_size;
    const float* pred_bb  = (const float*)d_in[0];
    const float* pred_lab = (const float*)d_in[1];
    const float* gt_bb    = (const float*)d_in[2];
    const int*   gt_lab   = (const int*)d_in[3];
    float* out = (float*)d_out;

    unsigned short* ah = (unsigned short*)d_ws;            // 32768*96*2 B = 6.29 MB
    float* acc = (float*)(ah + (size_t)BS * KPP * SK);     // pq[32], pp[32], qq[32], cnt

    hipLaunchKernelGGL(alpha_kernel, dim3(BS * KPP / 4), dim3(256), 0, stream,
                       pred_lab, ah, acc);
    hipLaunchKernelGGL(main_kernel, dim3(NALL), dim3(256), 0, stream,
                       pred_bb, ah, gt_bb, gt_lab, acc, out);
}

// Round 9
// 105.326 us; speedup vs baseline: 1.7229x; 1.0090x over previous
//
#include <hip/hip_runtime.h>
#include <math.h>

#define BS 32
#define KP 1000
#define KPP 1024         // padded rows per image (zero rows 1000..1023)
#define KG 100
#define NC 80
#define SK 96            // bf16 K stride (80 + 16 zero pad)
#define LP 104           // LDS row stride in shorts; shorts 96..103 hold the row's (mx,my,vx,vy) float4
#define NT 8             // ceil(KP/128)
#define NPAIR 36         // NT*(NT+1)/2
#define NQQ (BS * NPAIR) // 1152 qq tile blocks (dispatched FIRST)
#define NPPQ (5 * BS)    // 160 pp/pq blocks (dispatched last -> fill the tail)
#define NALL (NQQ + NPPQ)
#define NPERIMG 41       // 36 qq + 5 ppq blocks per image
// acc layout (floats): image b slot at b*16 (64 B line): [0]=pq [1]=pp [2]=qq [4]=img counter
// global counter at acc[512] (own line). Zeroed range: acc[0..767].
#define GCNT 512

using bf16x8 = __attribute__((ext_vector_type(8))) short;
using f32x4  = __attribute__((ext_vector_type(4))) float;
using f32x2  = __attribute__((ext_vector_type(2))) float;

__device__ __forceinline__ float wave_reduce_sum(float v) {
#pragma unroll
    for (int m = 32; m > 0; m >>= 1) v += __shfl_xor(v, m, 64);
    return v;
}
__device__ __forceinline__ float wave_reduce_max(float v) {
#pragma unroll
    for (int m = 32; m > 0; m >>= 1) v = fmaxf(v, __shfl_xor(v, m, 64));
    return v;
}

__device__ __forceinline__ unsigned short f2bf(float f) {   // RN-even
    unsigned int u = __float_as_uint(f);
    u += 0x7fffu + ((u >> 16) & 1u);
    return (unsigned short)(u >> 16);
}
__device__ __forceinline__ float bf2f(unsigned short h) {
    return __uint_as_float(((unsigned int)h) << 16);
}

// K_ij = N(m_i; m_j, v_i+v_j), diagonal 2-D. a,b = (mx, my, vx, vy)
__device__ __forceinline__ float kval(float4 a, float4 b) {
    f32x2 S = (f32x2){a.z, a.w} + (f32x2){b.z, b.w};
    f32x2 d = (f32x2){a.x, a.y} - (f32x2){b.x, b.y};
    f32x2 d2 = d * d;
    f32x2 t = d2 * S.yx;                 // dx^2*Sy , dy^2*Sx
    float num = t.x + t.y;
    float P = S.x * S.y;
    float rs = __builtin_amdgcn_rsqf(P);
    float q = num * rs * rs;             // num * rcp(P)
    return 0.15915494309189535f * rs * __expf(-0.5f * q);
}

// alpha[row][c] = sigmoid(l[80]) * softmax(l[0..79]) -> bf16, rows padded to
// 1024/image (pad rows zeroed). One wave per row. Block 0 zeroes acc[768].
__global__ __launch_bounds__(256) void alpha_kernel(const float* __restrict__ pl,
                                                    unsigned short* __restrict__ ah,
                                                    float* __restrict__ acc) {
    if (blockIdx.x == 0) {
#pragma unroll
        for (int k = 0; k < 3; ++k) acc[threadIdx.x + 256 * k] = 0.0f;
    }
    int wave = threadIdx.x >> 6;
    int lane = threadIdx.x & 63;
    int rr = blockIdx.x * 4 + wave;                   // < BS*KPP = 32768
    int b = rr >> 10, r = rr & (KPP - 1);
    unsigned short* oh = ah + (size_t)rr * SK;
    if (r < KP) {
        const float* x = pl + ((size_t)b * KP + r) * (NC + 1);
        float l0 = x[lane];
        float l1 = (lane < 16) ? x[64 + lane] : -1e30f;
        float obj = x[NC];
        float m = wave_reduce_max(fmaxf(l0, l1));
        float e0 = __expf(l0 - m);
        float e1 = (lane < 16) ? __expf(l1 - m) : 0.0f;
        float s = wave_reduce_sum(e0 + e1);
        float sig = 1.0f / (1.0f + __expf(-obj));
        float sc = sig / s;
        oh[lane] = f2bf(e0 * sc);
        if (lane < 32) oh[64 + lane] = (lane < 16) ? f2bf(e1 * sc) : 0;
    } else {
        oh[lane] = 0;
        if (lane < 32) oh[64 + lane] = 0;
    }
}

// Single main dispatch. Blocks [0,NQQ): qq 128x128 MFMA Gram tiles (triangular,
// off-diag x2), row params in the 16 B hole of each LDS row. Blocks [NQQ,NALL):
// pp/pq with alpha rows staged in LDS (stride SK=96 shorts -> 16B-aligned,
// linear contiguous copy of 3072 float4).
// Per-image 64B accumulator slots + hierarchical counters de-contend atomics.
__global__ __launch_bounds__(256, 3) void main_kernel(const float* __restrict__ pb,
                                                      const unsigned short* __restrict__ ahg,
                                                      const float* __restrict__ gtb,
                                                      const int* __restrict__ gtl,
                                                      float* __restrict__ acc,
                                                      float* __restrict__ out) {
    __shared__ short lds[2 * 128 * LP];   // 53,248 B, carved per path
    __shared__ float red[4];
    __shared__ int last;

    int tid = threadIdx.x;
    int lane = tid & 63, w = tid >> 6;
    int bi = blockIdx.x;
    int b;

    if (bi < NQQ) {
        // ---------------- qq path ----------------
        short* la = lds;
        short* lbb = lds + 128 * LP;
        int qi = bi;
        b = qi & 31;                     // consecutive blocks -> same XCD per image
        int t = qi >> 5;                 // 0..35
        int it = 0, rem = t;
        while (rem >= NT - it) { rem -= NT - it; ++it; }
        int jt = it + rem;
        int i0 = it * 128, j0 = jt * 128;

        // per-row params into the row holes (a-side -> la, b-side -> lbb)
        {
            int side = tid >> 7, r = tid & 127;
            int gi = (side ? j0 : i0) + r;
            float4 v = make_float4(0.0f, 0.0f, 1.0f, 1.0f);
            if (gi < KP) {
                float4 x = ((const float4*)pb)[b * KP + gi];
                v = make_float4(x.x, x.y, 0.25f * x.z * x.z, 0.25f * x.w * x.w);
            }
            short* L = side ? lbb : la;
            *(float4*)(L + r * LP + 96) = v;
        }

        // stage alpha tiles: 128 rows x 96 bf16 = contiguous 24576 B per side
        {
            const float4* sa = (const float4*)(ahg + ((size_t)(b << 10) + i0) * SK);
#pragma unroll
            for (int k = 0; k < 6; ++k) {
                int o = tid + k * 256;
                int row = o / 12, slot = o - row * 12;
                *(float4*)(la + row * LP + slot * 8) = sa[o];
            }
            if (jt != it) {
                const float4* sb = (const float4*)(ahg + ((size_t)(b << 10) + j0) * SK);
#pragma unroll
                for (int k = 0; k < 6; ++k) {
                    int o = tid + k * 256;
                    int row = o / 12, slot = o - row * 12;
                    *(float4*)(lbb + row * LP + slot * 8) = sb[o];
                }
            }
        }
        __syncthreads();
        const short* LB = (jt != it) ? lbb : la;

        int wy = w >> 1, wx = w & 1;
        int m15 = lane & 15, quad = lane >> 4;
        int ar = wy * 64 + m15;
        int br = wx * 64 + m15;

        f32x4 c4[4][4];
#pragma unroll
        for (int r = 0; r < 4; ++r)
#pragma unroll
            for (int s = 0; s < 4; ++s) c4[r][s] = (f32x4){0.0f, 0.0f, 0.0f, 0.0f};

#pragma unroll
        for (int ks = 0; ks < 3; ++ks) {
            int kk = ks * 32 + quad * 8;
            bf16x8 bh[4];
#pragma unroll
            for (int cg = 0; cg < 4; ++cg)
                bh[cg] = *(const bf16x8*)(LB + (br + cg * 16) * LP + kk);
#pragma unroll
            for (int rg = 0; rg < 4; ++rg) {
                bf16x8 xh = *(const bf16x8*)(la + (ar + rg * 16) * LP + kk);
#pragma unroll
                for (int cg = 0; cg < 4; ++cg)
                    c4[rg][cg] = __builtin_amdgcn_mfma_f32_16x16x32_bf16(xh, bh[cg], c4[rg][cg], 0, 0, 0);
            }
        }

        // epilogue: C/D layout col=lane&15 (b-side), row=quad*4+reg (a-side)
        float4 pj[4];
        int jb = wx * 64 + m15;
#pragma unroll
        for (int cg = 0; cg < 4; ++cg)
            pj[cg] = *(const float4*)(lbb + (jb + cg * 16) * LP + 96);
        float part = 0.0f;
        int ib = wy * 64 + quad * 4;
#pragma unroll
        for (int rg = 0; rg < 4; ++rg) {
#pragma unroll
            for (int e = 0; e < 4; ++e) {
                float4 pi = *(const float4*)(la + (ib + rg * 16 + e) * LP + 96);
#pragma unroll
                for (int cg = 0; cg < 4; ++cg)
                    part += c4[rg][cg][e] * kval(pi, pj[cg]);
            }
        }
        if (jt != it) part *= 2.0f;

        part = wave_reduce_sum(part);
        if (lane == 0) red[w] = part;
        __syncthreads();
        if (tid == 0)
            atomicAdd(&acc[b * 16 + 2], red[0] + red[1] + red[2] + red[3]);  // no return use
    } else {
        // ---------------- pp / pq path ----------------
        int pi = bi - NQQ;
        b = pi & 31;
        int p5 = pi >> 5;                // 0..3 = pq chunks, 4 = pp
        short* lalpha = lds;                        // 256 rows x 96 shorts = 49,152 B
        float4* gm = (float4*)(lds + 24576);        // byte 49,152 (16B-aligned), 1600 B
        int* gl = (int*)(lds + 24576 + 800);        // byte 50,752, 400 B
        if (tid < KG) {
            float4 x = ((const float4*)gtb)[b * KG + tid];
            gm[tid] = make_float4(x.x, x.y, 0.25f * x.z * x.z, 0.25f * x.w * x.w);
            gl[tid] = gtl[b * KG + tid];
        }
        if (p5 < 4) {
            // stage 256 alpha rows: contiguous 49,152 B, linear copy (3072 float4)
            const float4* sa = (const float4*)(ahg + ((size_t)(b << 10) + p5 * 256) * SK);
#pragma unroll
            for (int k = 0; k < 12; ++k) {
                int o = tid + k * 256;
                *(float4*)(lalpha + o * 8) = sa[o];
            }
        }
        __syncthreads();
        float part = 0.0f;
        if (p5 < 4) {
            int j = p5 * 256 + tid;
            if (j < KP) {
                float4 x = ((const float4*)pb)[b * KP + j];
                float4 pm = make_float4(x.x, x.y, 0.25f * x.z * x.z, 0.25f * x.w * x.w);
                const unsigned short* arow = (const unsigned short*)lalpha + tid * SK;
#pragma unroll 4
                for (int i = 0; i < KG; ++i) {
                    part += bf2f(arow[gl[i]]) * kval(gm[i], pm);
                }
            }
        } else {
            for (int p = tid; p < KG * KG; p += 256) {
                int i = p / KG;
                int j = p - i * KG;
                if (gl[i] == gl[j]) part += kval(gm[i], gm[j]);
            }
        }
        part = wave_reduce_sum(part);
        if (lane == 0) red[w] = part;
        __syncthreads();
        if (tid == 0) {
            float s = red[0] + red[1] + red[2] + red[3];
            atomicAdd(&acc[b * 16 + ((p5 < 4) ? 0 : 1)], s);   // no return use
        }
    }

    // ---------------- hierarchical finalize ----------------
    if (tid == 0) {
        __threadfence();
        unsigned int o = atomicAdd((unsigned int*)(acc + b * 16 + 4), 1u);
        int l = 0;
        if (o == NPERIMG - 1) {          // this image complete
            __threadfence();
            unsigned int g = atomicAdd((unsigned int*)(acc + GCNT), 1u);
            l = (g == BS - 1) ? 1 : 0;   // all images complete
        }
        last = l;
    }
    __syncthreads();
    if (last && tid < 64) {
        float v = 0.0f;
        if (tid < BS) {
            float pq = atomicAdd(&acc[tid * 16 + 0], 0.0f);   // coherent reads
            float pp = atomicAdd(&acc[tid * 16 + 1], 0.0f);
            float qq = atomicAdd(&acc[tid * 16 + 2], 0.0f);
            v = 2.0f * logf(pq) - logf(pp) - logf(qq);
        }
        v = wave_reduce_sum(v);
        if (tid == 0) out[0] = -v;
    }
}

extern "C" void kernel_launch(void* const* d_in, const int* in_sizes, int n_in,
                              void* d_out, int out_size, void* d_ws, size_t ws_size,
                              hipStream_t stream) {
    (void)in_sizes; (void)n_in; (void)out_size; (void)ws_size;
    const float* pred_bb  = (const float*)d_in[0];
    const float* pred_lab = (const float*)d_in[1];
    const float* gt_bb    = (const float*)d_in[2];
    const int*   gt_lab   = (const int*)d_in[3];
    float* out = (float*)d_out;

    unsigned short* ah = (unsigned short*)d_ws;            // 32768*96*2 B = 6.29 MB
    float* acc = (float*)(ah + (size_t)BS * KPP * SK);     // per-image slots + counters

    hipLaunchKernelGGL(alpha_kernel, dim3(BS * KPP / 4), dim3(256), 0, stream,
                       pred_lab, ah, acc);
    hipLaunchKernelGGL(main_kernel, dim3(NALL), dim3(256), 0, stream,
                       pred_bb, ah, gt_bb, gt_lab, acc, out);
}

// Round 10
// 99.222 us; speedup vs baseline: 1.8289x; 1.0615x over previous
//
#include <hip/hip_runtime.h>
#include <math.h>

#define BS 32
#define KP 1000
#define KPP 1024         // padded rows per image (zero rows 1000..1023)
#define KG 100
#define NC 80
#define SK 96            // bf16 K stride (80 + 16 zero pad)
#define LP 104           // LDS row stride in shorts; shorts 96..103 hold the row's (mx,my,vx,vy) float4
#define NT 8             // ceil(KP/128)
#define NIT 15           // (it,half) pairs per image: (0,0),(0,1)...(6,1),(7,0)
#define NQQ (BS * NIT)   // 480 qq blocks (dispatched FIRST), each streams 1..4 jt tiles
#define NPPQ (5 * BS)    // 160 pp/pq blocks (dispatched last -> fill the tail)
#define NALL (NQQ + NPPQ)
#define NPERIMG 20       // 15 qq + 5 ppq blocks per image
// acc layout (floats): image b slot at b*16 (64 B line): [0]=pq [1]=pp [2]=qq [4]=img counter
// global counter at acc[512] (own line). Zeroed range: acc[0..767].
#define GCNT 512

using bf16x8 = __attribute__((ext_vector_type(8))) short;
using f32x4  = __attribute__((ext_vector_type(4))) float;
using f32x2  = __attribute__((ext_vector_type(2))) float;

__device__ __forceinline__ float wave_reduce_sum(float v) {
#pragma unroll
    for (int m = 32; m > 0; m >>= 1) v += __shfl_xor(v, m, 64);
    return v;
}
__device__ __forceinline__ float wave_reduce_max(float v) {
#pragma unroll
    for (int m = 32; m > 0; m >>= 1) v = fmaxf(v, __shfl_xor(v, m, 64));
    return v;
}

__device__ __forceinline__ unsigned short f2bf(float f) {   // RN-even
    unsigned int u = __float_as_uint(f);
    u += 0x7fffu + ((u >> 16) & 1u);
    return (unsigned short)(u >> 16);
}
__device__ __forceinline__ float bf2f(unsigned short h) {
    return __uint_as_float(((unsigned int)h) << 16);
}

// K_ij = N(m_i; m_j, v_i+v_j), diagonal 2-D. a,b = (mx, my, vx, vy)
__device__ __forceinline__ float kval(float4 a, float4 b) {
    f32x2 S = (f32x2){a.z, a.w} + (f32x2){b.z, b.w};
    f32x2 d = (f32x2){a.x, a.y} - (f32x2){b.x, b.y};
    f32x2 d2 = d * d;
    f32x2 t = d2 * S.yx;                 // dx^2*Sy , dy^2*Sx
    float num = t.x + t.y;
    float P = S.x * S.y;
    float rs = __builtin_amdgcn_rsqf(P);
    float q = num * rs * rs;             // num * rcp(P)
    return 0.15915494309189535f * rs * __expf(-0.5f * q);
}

// alpha[row][c] = sigmoid(l[80]) * softmax(l[0..79]) -> bf16, rows padded to
// 1024/image (pad rows zeroed). One wave per row. Block 0 zeroes acc[768].
__global__ __launch_bounds__(256) void alpha_kernel(const float* __restrict__ pl,
                                                    unsigned short* __restrict__ ah,
                                                    float* __restrict__ acc) {
    if (blockIdx.x == 0) {
#pragma unroll
        for (int k = 0; k < 3; ++k) acc[threadIdx.x + 256 * k] = 0.0f;
    }
    int wave = threadIdx.x >> 6;
    int lane = threadIdx.x & 63;
    int rr = blockIdx.x * 4 + wave;                   // < BS*KPP = 32768
    int b = rr >> 10, r = rr & (KPP - 1);
    unsigned short* oh = ah + (size_t)rr * SK;
    if (r < KP) {
        const float* x = pl + ((size_t)b * KP + r) * (NC + 1);
        float l0 = x[lane];
        float l1 = (lane < 16) ? x[64 + lane] : -1e30f;
        float obj = x[NC];
        float m = wave_reduce_max(fmaxf(l0, l1));
        float e0 = __expf(l0 - m);
        float e1 = (lane < 16) ? __expf(l1 - m) : 0.0f;
        float s = wave_reduce_sum(e0 + e1);
        float sig = 1.0f / (1.0f + __expf(-obj));
        float sc = sig / s;
        oh[lane] = f2bf(e0 * sc);
        if (lane < 32) oh[64 + lane] = (lane < 16) ? f2bf(e1 * sc) : 0;
    } else {
        oh[lane] = 0;
        if (lane < 32) oh[64 + lane] = 0;
    }
}

// Single main dispatch.
// Blocks [0,NQQ): qq. Block (b, it, half) stages its A-tile (128 rows) ONCE,
// then streams B-tiles jt = it+half, +2, ... < 8, doing the 128x128 MFMA Gram
// + kval epilogue per tile (off-diag x2). Amortizes staging/launch/finalize
// over up to 4 tiles; 640 total blocks <= 768 resident slots -> 1 round.
// Blocks [NQQ,NALL): pp/pq with alpha rows staged in LDS.
// Per-image 64B accumulator slots + hierarchical counters.
__global__ __launch_bounds__(256, 3) void main_kernel(const float* __restrict__ pb,
                                                      const unsigned short* __restrict__ ahg,
                                                      const float* __restrict__ gtb,
                                                      const int* __restrict__ gtl,
                                                      float* __restrict__ acc,
                                                      float* __restrict__ out) {
    __shared__ short lds[2 * 128 * LP];   // 53,248 B, carved per path
    __shared__ float red[4];
    __shared__ int last;

    int tid = threadIdx.x;
    int lane = tid & 63, w = tid >> 6;
    int bi = blockIdx.x;
    int b;

    if (bi < NQQ) {
        // ---------------- qq path ----------------
        short* la = lds;
        short* lb = lds + 128 * LP;
        b = bi & 31;                     // consecutive blocks spread images -> XCD locality
        int p = bi >> 5;                 // 0..14
        int it = p >> 1, half = p & 1;
        int i0 = it * 128;

        // stage A-tile once: params into la holes + 96-col alpha rows
        if (tid < 128) {
            int gi = i0 + tid;
            float4 v = make_float4(0.0f, 0.0f, 1.0f, 1.0f);
            if (gi < KP) {
                float4 x = ((const float4*)pb)[b * KP + gi];
                v = make_float4(x.x, x.y, 0.25f * x.z * x.z, 0.25f * x.w * x.w);
            }
            *(float4*)(la + tid * LP + 96) = v;
        }
        {
            const float4* sa = (const float4*)(ahg + ((size_t)(b << 10) + i0) * SK);
#pragma unroll
            for (int k = 0; k < 6; ++k) {
                int o = tid + k * 256;
                int row = o / 12, slot = o - row * 12;
                *(float4*)(la + row * LP + slot * 8) = sa[o];
            }
        }

        int wy = w >> 1, wx = w & 1;
        int m15 = lane & 15, quad = lane >> 4;
        int ar = wy * 64 + m15;
        int br = wx * 64 + m15;
        int jb = wx * 64 + m15;
        int ib = wy * 64 + quad * 4;

        float part = 0.0f;
        bool first = true;
        for (int jt = it + half; jt < NT; jt += 2) {
            int j0 = jt * 128;
            if (!first) __syncthreads();     // previous tile's lb readers done
            // stage B-tile: params into lb holes + alpha rows
            if (tid < 128) {
                int gi = j0 + tid;
                float4 v = make_float4(0.0f, 0.0f, 1.0f, 1.0f);
                if (gi < KP) {
                    float4 x = ((const float4*)pb)[b * KP + gi];
                    v = make_float4(x.x, x.y, 0.25f * x.z * x.z, 0.25f * x.w * x.w);
                }
                *(float4*)(lb + tid * LP + 96) = v;
            }
            {
                const float4* sb = (const float4*)(ahg + ((size_t)(b << 10) + j0) * SK);
#pragma unroll
                for (int k = 0; k < 6; ++k) {
                    int o = tid + k * 256;
                    int row = o / 12, slot = o - row * 12;
                    *(float4*)(lb + row * LP + slot * 8) = sb[o];
                }
            }
            __syncthreads();                 // lb (and la on first iter) visible

            f32x4 c4[4][4];
#pragma unroll
            for (int r = 0; r < 4; ++r)
#pragma unroll
                for (int s = 0; s < 4; ++s) c4[r][s] = (f32x4){0.0f, 0.0f, 0.0f, 0.0f};

#pragma unroll
            for (int ks = 0; ks < 3; ++ks) {
                int kk = ks * 32 + quad * 8;
                bf16x8 bh[4];
#pragma unroll
                for (int cg = 0; cg < 4; ++cg)
                    bh[cg] = *(const bf16x8*)(lb + (br + cg * 16) * LP + kk);
#pragma unroll
                for (int rg = 0; rg < 4; ++rg) {
                    bf16x8 xh = *(const bf16x8*)(la + (ar + rg * 16) * LP + kk);
#pragma unroll
                    for (int cg = 0; cg < 4; ++cg)
                        c4[rg][cg] = __builtin_amdgcn_mfma_f32_16x16x32_bf16(xh, bh[cg], c4[rg][cg], 0, 0, 0);
                }
            }

            // epilogue: C/D layout col=lane&15 (b-side), row=quad*4+reg (a-side)
            float4 pj[4];
#pragma unroll
            for (int cg = 0; cg < 4; ++cg)
                pj[cg] = *(const float4*)(lb + (jb + cg * 16) * LP + 96);
            float tpart = 0.0f;
#pragma unroll
            for (int rg = 0; rg < 4; ++rg) {
#pragma unroll
                for (int e = 0; e < 4; ++e) {
                    float4 pi = *(const float4*)(la + (ib + rg * 16 + e) * LP + 96);
#pragma unroll
                    for (int cg = 0; cg < 4; ++cg)
                        tpart += c4[rg][cg][e] * kval(pi, pj[cg]);
                }
            }
            part += (jt != it) ? 2.0f * tpart : tpart;
            first = false;
        }

        part = wave_reduce_sum(part);
        if (lane == 0) red[w] = part;
        __syncthreads();
        if (tid == 0)
            atomicAdd(&acc[b * 16 + 2], red[0] + red[1] + red[2] + red[3]);  // no return use
    } else {
        // ---------------- pp / pq path ----------------
        int pi = bi - NQQ;
        b = pi & 31;
        int p5 = pi >> 5;                // 0..3 = pq chunks, 4 = pp
        short* lalpha = lds;                        // 256 rows x 96 shorts = 49,152 B
        float4* gm = (float4*)(lds + 24576);        // byte 49,152 (16B-aligned), 1600 B
        int* gl = (int*)(lds + 24576 + 800);        // byte 50,752, 400 B
        if (tid < KG) {
            float4 x = ((const float4*)gtb)[b * KG + tid];
            gm[tid] = make_float4(x.x, x.y, 0.25f * x.z * x.z, 0.25f * x.w * x.w);
            gl[tid] = gtl[b * KG + tid];
        }
        if (p5 < 4) {
            // stage 256 alpha rows: contiguous 49,152 B, linear copy (3072 float4)
            const float4* sa = (const float4*)(ahg + ((size_t)(b << 10) + p5 * 256) * SK);
#pragma unroll
            for (int k = 0; k < 12; ++k) {
                int o = tid + k * 256;
                *(float4*)(lalpha + o * 8) = sa[o];
            }
        }
        __syncthreads();
        float part = 0.0f;
        if (p5 < 4) {
            int j = p5 * 256 + tid;
            if (j < KP) {
                float4 x = ((const float4*)pb)[b * KP + j];
                float4 pm = make_float4(x.x, x.y, 0.25f * x.z * x.z, 0.25f * x.w * x.w);
                const unsigned short* arow = (const unsigned short*)lalpha + tid * SK;
#pragma unroll 4
                for (int i = 0; i < KG; ++i) {
                    part += bf2f(arow[gl[i]]) * kval(gm[i], pm);
                }
            }
        } else {
            for (int p = tid; p < KG * KG; p += 256) {
                int i = p / KG;
                int j = p - i * KG;
                if (gl[i] == gl[j]) part += kval(gm[i], gm[j]);
            }
        }
        part = wave_reduce_sum(part);
        if (lane == 0) red[w] = part;
        __syncthreads();
        if (tid == 0) {
            float s = red[0] + red[1] + red[2] + red[3];
            atomicAdd(&acc[b * 16 + ((p5 < 4) ? 0 : 1)], s);   // no return use
        }
    }

    // ---------------- hierarchical finalize ----------------
    if (tid == 0) {
        __threadfence();
        unsigned int o = atomicAdd((unsigned int*)(acc + b * 16 + 4), 1u);
        int l = 0;
        if (o == NPERIMG - 1) {          // this image complete
            __threadfence();
            unsigned int g = atomicAdd((unsigned int*)(acc + GCNT), 1u);
            l = (g == BS - 1) ? 1 : 0;   // all images complete
        }
        last = l;
    }
    __syncthreads();
    if (last && tid < 64) {
        float v = 0.0f;
        if (tid < BS) {
            float pq = atomicAdd(&acc[tid * 16 + 0], 0.0f);   // coherent reads
            float pp = atomicAdd(&acc[tid * 16 + 1], 0.0f);
            float qq = atomicAdd(&acc[tid * 16 + 2], 0.0f);
            v = 2.0f * logf(pq) - logf(pp) - logf(qq);
        }
        v = wave_reduce_sum(v);
        if (tid == 0) out[0] = -v;
    }
}

extern "C" void kernel_launch(void* const* d_in, const int* in_sizes, int n_in,
                              void* d_out, int out_size, void* d_ws, size_t ws_size,
                              hipStream_t stream) {
    (void)in_sizes; (void)n_in; (void)out_size; (void)ws_size;
    const float* pred_bb  = (const float*)d_in[0];
    const float* pred_lab = (const float*)d_in[1];
    const float* gt_bb    = (const float*)d_in[2];
    const int*   gt_lab   = (const int*)d_in[3];
    float* out = (float*)d_out;

    unsigned short* ah = (unsigned short*)d_ws;            // 32768*96*2 B = 6.29 MB
    float* acc = (float*)(ah + (size_t)BS * KPP * SK);     // per-image slots + counters

    hipLaunchKernelGGL(alpha_kernel, dim3(BS * KPP / 4), dim3(256), 0, stream,
                       pred_lab, ah, acc);
    hipLaunchKernelGGL(main_kernel, dim3(NALL), dim3(256), 0, stream,
                       pred_bb, ah, gt_bb, gt_lab, acc, out);
}